// Round 1
// baseline (1240.803 us; speedup 1.0000x reference)
//
#include <hip/hip_runtime.h>
#include <hip/hip_bf16.h>

// Problem: int8-quantized 3x3 conv, N=8, C=K=32, H=W=512, pad=1, NCHW/OIHW.
// q = clip(rintf(t * 127/max|t|), -127, 127); out = conv(qx,qw)*sx*sw/127^2 + bias.

#define H 512
#define W 512
#define CIN 32
#define KOUT 32
#define NB 8
#define TH 16
#define TW 32

__device__ __forceinline__ int dot4(int a, int b, int c) {
    return __builtin_amdgcn_sdot4(a, b, c, false);
}

__global__ void init_slots(unsigned* slots) {
    if (threadIdx.x < 2) slots[threadIdx.x] = 0u;
}

// max|x| over 67.1M floats, float4 grid-stride, wave+block reduce, 1 atomic/block
__global__ void absmax_x(const float4* __restrict__ x, unsigned* slots, int n4) {
    float m = 0.f;
    for (int i = blockIdx.x * blockDim.x + threadIdx.x; i < n4;
         i += gridDim.x * blockDim.x) {
        float4 v = x[i];
        m = fmaxf(m, fmaxf(fmaxf(fabsf(v.x), fabsf(v.y)),
                           fmaxf(fabsf(v.z), fabsf(v.w))));
    }
    #pragma unroll
    for (int off = 32; off > 0; off >>= 1)
        m = fmaxf(m, __shfl_down(m, off));
    __shared__ float wm[4];
    int lane = threadIdx.x & 63, wid = threadIdx.x >> 6;
    if (lane == 0) wm[wid] = m;
    __syncthreads();
    if (threadIdx.x == 0) {
        m = fmaxf(fmaxf(wm[0], wm[1]), fmaxf(wm[2], wm[3]));
        atomicMax(slots, __float_as_uint(m));  // all values >= 0: uint order == float order
    }
}

// max|w| over 9216 floats, single block
__global__ void absmax_w(const float* __restrict__ w, unsigned* slots, int n) {
    float m = 0.f;
    for (int i = threadIdx.x; i < n; i += blockDim.x)
        m = fmaxf(m, fabsf(w[i]));
    #pragma unroll
    for (int off = 32; off > 0; off >>= 1)
        m = fmaxf(m, __shfl_down(m, off));
    __shared__ float wm[4];
    int lane = threadIdx.x & 63, wid = threadIdx.x >> 6;
    if (lane == 0) wm[wid] = m;
    __syncthreads();
    if (threadIdx.x == 0) {
        m = fmaxf(fmaxf(wm[0], wm[1]), fmaxf(wm[2], wm[3]));
        atomicMax(slots + 1, __float_as_uint(m));
    }
}

// Fused quantize + int8 conv + dequant + bias.
// Block: 256 threads, output tile TW x TH (32x16), all 32 output channels.
// LDS act: [c/4][y(18)][x(34)] dwords (4 packed int8 c's). 4896 dw = 19584 B.
// LDS wgt: [k][tap][c/4] dwords. 2304 dw = 9216 B.
__global__ __launch_bounds__(256)
void conv_k(const float* __restrict__ x, const float* __restrict__ w,
            const float* __restrict__ bias, const unsigned* __restrict__ slots,
            float* __restrict__ out) {
    __shared__ int lds_a[8 * 18 * 34];
    __shared__ int lds_w[KOUT * 9 * 8];

    const int tid = threadIdx.x;
    const int n  = blockIdx.z;
    const int y0 = blockIdx.y * TH;
    const int x0 = blockIdx.x * TW;

    const float sx = __uint_as_float(slots[0]);
    const float sw = __uint_as_float(slots[1]);
    const float qsx = 127.f / sx;
    const float qsw = 127.f / sw;

    // quantize weights into LDS (per block; reads hit L2, 9216 floats)
    {
        char* lw = (char*)lds_w;
        for (int fw = tid; fw < KOUT * CIN * 9; fw += 256) {
            int k = fw / (CIN * 9);
            int rem = fw % (CIN * 9);
            int c = rem / 9;
            int tap = rem % 9;
            float qf = fminf(fmaxf(rintf(w[fw] * qsw), -127.f), 127.f);
            lw[(((k * 9 + tap) * 8 + (c >> 2)) << 2) + (c & 3)] = (char)(int)qf;
        }
    }
    // load + quantize activation tile (18 x 34 halo) for all 32 c
    {
        char* la = (char*)lds_a;
        const float* xb = x + (size_t)n * CIN * H * W;
        for (int e = tid; e < CIN * 18 * 34; e += 256) {
            int c = e / 612;
            int rem = e % 612;
            int yy = rem / 34;
            int xx = rem % 34;
            int gy = y0 + yy - 1, gx = x0 + xx - 1;
            float v = 0.f;
            if ((unsigned)gy < (unsigned)H && (unsigned)gx < (unsigned)W)
                v = xb[(c * H + gy) * W + gx];
            float qf = fminf(fmaxf(rintf(v * qsx), -127.f), 127.f);
            la[(((c >> 2) * 612 + yy * 34 + xx) << 2) + (c & 3)] = (char)(int)qf;
        }
    }
    __syncthreads();

    const int kg = tid >> 6;          // 0..3: k group of 8
    const int lane = tid & 63;        // pixel base; pixels lane + 64*j
    const int b = (lane >> 5) * 34 + (lane & 31);  // LDS pixel base addr (dwords)

    int acc[8][8];
    #pragma unroll
    for (int kk = 0; kk < 8; ++kk)
        #pragma unroll
        for (int j = 0; j < 8; ++j) acc[kk][j] = 0;

    #pragma unroll
    for (int dy = 0; dy < 3; ++dy) {
        #pragma unroll
        for (int dx = 0; dx < 3; ++dx) {
            const int tap = dy * 3 + dx;
            #pragma unroll
            for (int i = 0; i < 8; ++i) {
                int a[8];
                #pragma unroll
                for (int j = 0; j < 8; ++j)
                    a[j] = lds_a[b + i * 612 + (2 * j + dy) * 34 + dx];
                int wv[8];
                #pragma unroll
                for (int kk = 0; kk < 8; ++kk)
                    wv[kk] = lds_w[((kg * 8 + kk) * 9 + tap) * 8 + i];
                #pragma unroll
                for (int kk = 0; kk < 8; ++kk)
                    #pragma unroll
                    for (int j = 0; j < 8; ++j)
                        acc[kk][j] = dot4(a[j], wv[kk], acc[kk][j]);
            }
        }
    }

    const float dscale = (sx * sw) / (127.f * 127.f);
    const int px = lane & 31;
    #pragma unroll
    for (int kk = 0; kk < 8; ++kk) {
        const int k = kg * 8 + kk;
        const float bv = bias[k];
        float* ob = out + (((size_t)(n * KOUT + k) * H + y0) * W + x0);
        #pragma unroll
        for (int j = 0; j < 8; ++j) {
            int pyj = (lane >> 5) + 2 * j;
            ob[pyj * W + px] = (float)acc[kk][j] * dscale + bv;
        }
    }
}

extern "C" void kernel_launch(void* const* d_in, const int* in_sizes, int n_in,
                              void* d_out, int out_size, void* d_ws, size_t ws_size,
                              hipStream_t stream) {
    const float* x    = (const float*)d_in[0];
    const float* w    = (const float*)d_in[1];
    const float* bias = (const float*)d_in[2];
    float* out        = (float*)d_out;
    unsigned* slots   = (unsigned*)d_ws;

    hipLaunchKernelGGL(init_slots, dim3(1), dim3(64), 0, stream, slots);
    hipLaunchKernelGGL(absmax_x, dim3(4096), dim3(256), 0, stream,
                       (const float4*)x, slots, (NB * CIN * H * W) / 4);
    hipLaunchKernelGGL(absmax_w, dim3(1), dim3(256), 0, stream,
                       w, slots, KOUT * CIN * 9);
    dim3 grid(W / TW, H / TH, NB);
    hipLaunchKernelGGL(conv_k, grid, dim3(256), 0, stream, x, w, bias, slots, out);
}

// Round 2
// 580.250 us; speedup vs baseline: 2.1384x; 2.1384x over previous
//
#include <hip/hip_runtime.h>
#include <hip/hip_bf16.h>

// int8-quantized 3x3 conv, N=8, C=K=32, H=W=512, pad=1, NCHW/OIHW.
// q = clip(rint(t*127/max|t|), -127, 127); out = conv(qx,qw)*sx*sw/127^2 + bias.
// Round 2: int8 MFMA (32x32x32) im2col-by-tap; weights pre-quantized to d_ws.

#define H 512
#define W 512
#define CIN 32
#define KOUT 32
#define NB 8
#define TH 16
#define TW 32

typedef int v4i  __attribute__((ext_vector_type(4)));
typedef int v16i __attribute__((ext_vector_type(16)));

__global__ void init_slots(unsigned* slots) {
    if (threadIdx.x < 2) slots[threadIdx.x] = 0u;
}

__device__ __forceinline__ float max4(float4 v) {
    return fmaxf(fmaxf(fabsf(v.x), fabsf(v.y)), fmaxf(fabsf(v.z), fabsf(v.w)));
}

// max|x| over 16.78M float4s. 2048 blocks x 256 thr, 4-deep unroll, indep accumulators.
__global__ __launch_bounds__(256)
void absmax_x(const float4* __restrict__ x, unsigned* slots, int n4) {
    const int stride = gridDim.x * blockDim.x;
    int i = blockIdx.x * blockDim.x + threadIdx.x;
    float m0 = 0.f, m1 = 0.f, m2 = 0.f, m3 = 0.f;
    for (; i + 3 * stride < n4; i += 4 * stride) {
        float4 a = x[i], b = x[i + stride], c = x[i + 2 * stride], d = x[i + 3 * stride];
        m0 = fmaxf(m0, max4(a)); m1 = fmaxf(m1, max4(b));
        m2 = fmaxf(m2, max4(c)); m3 = fmaxf(m3, max4(d));
    }
    for (; i < n4; i += stride) m0 = fmaxf(m0, max4(x[i]));
    float m = fmaxf(fmaxf(m0, m1), fmaxf(m2, m3));
    #pragma unroll
    for (int off = 32; off > 0; off >>= 1)
        m = fmaxf(m, __shfl_down(m, off));
    __shared__ float wm[4];
    int lane = threadIdx.x & 63, wid = threadIdx.x >> 6;
    if (lane == 0) wm[wid] = m;
    __syncthreads();
    if (threadIdx.x == 0) {
        m = fmaxf(fmaxf(wm[0], wm[1]), fmaxf(wm[2], wm[3]));
        atomicMax(slots, __float_as_uint(m));  // values >= 0: uint order == float order
    }
}

// One block: max|w| reduce -> slots[1], then quantize+pack w into qw[tap][kout][c] bytes.
__global__ __launch_bounds__(256)
void prep_w(const float* __restrict__ w, unsigned* slots, int* __restrict__ qw) {
    float m = 0.f;
    for (int i = threadIdx.x; i < KOUT * CIN * 9; i += 256)
        m = fmaxf(m, fabsf(w[i]));
    #pragma unroll
    for (int off = 32; off > 0; off >>= 1)
        m = fmaxf(m, __shfl_down(m, off));
    __shared__ float wm[4];
    __shared__ float swsh;
    int lane = threadIdx.x & 63, wid = threadIdx.x >> 6;
    if (lane == 0) wm[wid] = m;
    __syncthreads();
    if (threadIdx.x == 0) {
        float t = fmaxf(fmaxf(wm[0], wm[1]), fmaxf(wm[2], wm[3]));
        slots[1] = __float_as_uint(t);
        swsh = t;
    }
    __syncthreads();
    const float qs = 127.f / swsh;
    // dword d: tap = d>>8, k = (d>>3)&31, c4 = d&7; packs c = 4*c4 + 0..3
    for (int d = threadIdx.x; d < 9 * KOUT * 8; d += 256) {
        int tap = d >> 8, rem = d & 255, k = rem >> 3, c4 = rem & 7;
        int pk = 0;
        #pragma unroll
        for (int i = 0; i < 4; ++i) {
            int c = c4 * 4 + i;
            float q = fminf(fmaxf(rintf(w[(k * CIN + c) * 9 + tap] * qs), -127.f), 127.f);
            pk |= ((int)q & 255) << (8 * i);
        }
        qw[d] = pk;
    }
}

// Fused quantize-x + int8 MFMA conv + dequant + bias.
// Block: 256 thr (4 waves). Tile: 32 (x) x 16 (y), all 32 kout, one n.
// LDS act: [yy(18)][xx(34)][c(32)] bytes = 19584 B; B-frag = one ds_read_b128.
// Weights: fragments straight from global qw (L1-hot, 9216 B shared by all blocks).
__global__ __launch_bounds__(256)
void conv_mfma(const float* __restrict__ x, const int* __restrict__ qw,
               const float* __restrict__ bias, const unsigned* __restrict__ slots,
               float* __restrict__ out) {
    __shared__ int lds_a[18 * 34 * 8];  // dword per (pixel, c4)

    const int tid = threadIdx.x;
    const int n  = blockIdx.z;
    const int y0 = blockIdx.y * TH;
    const int x0 = blockIdx.x * TW;

    const float sx = __uint_as_float(slots[0]);
    const float sw = __uint_as_float(slots[1]);
    const float qsx = 127.f / sx;

    // ---- stage + quantize activation tile (18x34 halo, 32 c) ----
    const float* xb = x + (size_t)n * CIN * H * W;
    for (int e = tid; e < 8 * 612; e += 256) {
        int c4  = e / 612;          // 0..7  (pixel-major => coalesced x reads)
        int pix = e - c4 * 612;     // 0..611
        int yy  = pix / 34;
        int xx  = pix - yy * 34;
        int gy = y0 + yy - 1, gx = x0 + xx - 1;
        bool ok = ((unsigned)gy < (unsigned)H) & ((unsigned)gx < (unsigned)W);
        const float* p = xb + ((size_t)(c4 * 4) * H + gy) * W + gx;
        int pk = 0;
        #pragma unroll
        for (int i = 0; i < 4; ++i) {
            float v = ok ? p[(size_t)i * H * W] : 0.f;
            int q = (int)fminf(fmaxf(rintf(v * qsx), -127.f), 127.f);
            pk |= (q & 255) << (8 * i);
        }
        lds_a[pix * 8 + c4] = pk;
    }

    // ---- weight A-fragments: A[m=kout][k=c], kout = lane&31, c = 16*half + j ----
    const int lane = tid & 63;
    const int kcol = lane & 31;     // kout for A; pixel-x col for B; out col
    const int half = lane >> 5;
    const v4i* qwv = (const v4i*)qw;  // 16B unit index: (tap*32 + kout)*2 + half
    v4i wf[9];
    #pragma unroll
    for (int t = 0; t < 9; ++t)
        wf[t] = qwv[(t * KOUT + kcol) * 2 + half];

    __syncthreads();

    // ---- MFMA main: wave handles 4 output rows; reuse LDS rows across dy ----
    const int wvid  = tid >> 6;
    const int ybase = wvid * 4;                 // local output rows ybase..ybase+3
    const v4i* lap = (const v4i*)lds_a;         // 16B unit: (yy*34 + xx)*2 + half

    v16i acc[4];
    #pragma unroll
    for (int r = 0; r < 4; ++r)
        #pragma unroll
        for (int q = 0; q < 16; ++q) acc[r][q] = 0;

    #pragma unroll
    for (int q = 0; q < 6; ++q) {               // LDS row = ybase + q (input rows)
        const int ly = ybase + q;
        v4i b[3];
        #pragma unroll
        for (int dx = 0; dx < 3; ++dx)
            b[dx] = lap[(ly * 34 + kcol + dx) * 2 + half];
        #pragma unroll
        for (int dy = 0; dy < 3; ++dy) {
            const int r = q - dy;               // output row using this LDS row
            if (r >= 0 && r < 4) {
                #pragma unroll
                for (int dx = 0; dx < 3; ++dx)
                    acc[r] = __builtin_amdgcn_mfma_i32_32x32x32_i8(
                        wf[dy * 3 + dx], b[dx], acc[r], 0, 0, 0);
            }
        }
    }

    // ---- epilogue: dequant + bias; D row m = kout, col n = x ----
    const float dscale = sx * sw * (1.f / 16129.f);
    float bv[16];
    #pragma unroll
    for (int reg = 0; reg < 16; ++reg)
        bv[reg] = bias[(reg & 3) + 8 * (reg >> 2) + 4 * half];

    #pragma unroll
    for (int r = 0; r < 4; ++r) {
        const int ygl = y0 + ybase + r;
        float* ob = out + (((size_t)n * KOUT * H + ygl) * W) + x0 + kcol;
        #pragma unroll
        for (int reg = 0; reg < 16; ++reg) {
            const int m = (reg & 3) + 8 * (reg >> 2) + 4 * half;  // kout
            ob[(size_t)m * H * W] = (float)acc[r][reg] * dscale + bv[reg];
        }
    }
}

extern "C" void kernel_launch(void* const* d_in, const int* in_sizes, int n_in,
                              void* d_out, int out_size, void* d_ws, size_t ws_size,
                              hipStream_t stream) {
    const float* x    = (const float*)d_in[0];
    const float* w    = (const float*)d_in[1];
    const float* bias = (const float*)d_in[2];
    float* out        = (float*)d_out;
    unsigned* slots   = (unsigned*)d_ws;
    int* qw           = (int*)((char*)d_ws + 16);  // 9216 B packed int8 weights

    hipLaunchKernelGGL(init_slots, dim3(1), dim3(64), 0, stream, slots);
    hipLaunchKernelGGL(absmax_x, dim3(2048), dim3(256), 0, stream,
                       (const float4*)x, slots, (NB * CIN * H * W) / 4);
    hipLaunchKernelGGL(prep_w, dim3(1), dim3(256), 0, stream, w, slots, qw);
    dim3 grid(W / TW, H / TH, NB);
    hipLaunchKernelGGL(conv_mfma, grid, dim3(256), 0, stream, x, qw, bias, slots, out);
}